// Round 1
// baseline (113.318 us; speedup 1.0000x reference)
//
#include <hip/hip_runtime.h>

// WTA_layer_Neuron: x [T=36, B=32, H=64, N=1024] f32 -> spikes (same shape).
// One wave (64 lanes) per (b,h) pair: 2048 pairs, 16 neurons/lane.
// Per-pair state: v[16] per lane, block bitmask per lane, block_input scalar.
// th is data-independent: V_TH0 * 2^-max(0, t-12).

constexpr int T_TOTAL = 36;
constexpr int T_FIRE0 = 12;          // START + WAIT
constexpr int NPAIR   = 32 * 64;     // B * H = 2048
constexpr int NN      = 1024;        // neurons per pair

__global__ __launch_bounds__(256) void wta_kernel(const float* __restrict__ x,
                                                  float* __restrict__ out) {
    const int gtid = blockIdx.x * 256 + threadIdx.x;
    const int pair = gtid >> 6;                  // wave id = (b,h) pair
    const int lane = threadIdx.x & 63;
    const size_t pair_off = (size_t)pair * NN;

    float v[16];
#pragma unroll
    for (int i = 0; i < 16; ++i) v[i] = 0.0f;
    unsigned blockmask = 0;                      // bit i: neuron 4*k+j fired before
    float bi = 1.0f;                             // block_input (wave-uniform)

    // V_TH0 = 2^23 / (1/ln 2) / 2, computed in f64 exactly as numpy does.
    const double ln2 = 0.6931471805599453;      // np.log(2.0)
    const double log_base = 1.0 / ln2;
    float th = (float)(8388608.0 / log_base / 2.0);

    // ---- Phase 1: t in [0,12) -- charge only, output is all zeros ----
    for (int t = 0; t < T_FIRE0; ++t) {
        const float* xt = x + ((size_t)t * NPAIR) * NN + pair_off;
        float4 xa[4];
#pragma unroll
        for (int k = 0; k < 4; ++k)
            xa[k] = *(const float4*)(xt + 4 * lane + 256 * k);

        float m = xa[0].x;
#pragma unroll
        for (int k = 0; k < 4; ++k)
            m = fmaxf(m, fmaxf(fmaxf(xa[k].x, xa[k].y), fmaxf(xa[k].z, xa[k].w)));
#pragma unroll
        for (int off = 32; off >= 1; off >>= 1)
            m = fmaxf(m, __shfl_xor(m, off, 64));

        const float sub = m * bi;                // exact: bi in {0,1}
#pragma unroll
        for (int k = 0; k < 4; ++k) {
            v[4 * k + 0] += xa[k].x - sub;
            v[4 * k + 1] += xa[k].y - sub;
            v[4 * k + 2] += xa[k].z - sub;
            v[4 * k + 3] += xa[k].w - sub;
        }
        if (m > 0.0f) bi = 0.0f;

        float* ot = out + ((size_t)t * NPAIR) * NN + pair_off;
        const float4 z = make_float4(0.f, 0.f, 0.f, 0.f);
#pragma unroll
        for (int k = 0; k < 4; ++k)
            *(float4*)(ot + 4 * lane + 256 * k) = z;
    }

    // ---- Phase 2: t in [12,36) -- fire + WTA output blocking ----
    for (int t = T_FIRE0; t < T_TOTAL; ++t) {
        const float* xt = x + ((size_t)t * NPAIR) * NN + pair_off;
        float4 xa[4];
#pragma unroll
        for (int k = 0; k < 4; ++k)
            xa[k] = *(const float4*)(xt + 4 * lane + 256 * k);

        float m = xa[0].x;
#pragma unroll
        for (int k = 0; k < 4; ++k)
            m = fmaxf(m, fmaxf(fmaxf(xa[k].x, xa[k].y), fmaxf(xa[k].z, xa[k].w)));
#pragma unroll
        for (int off = 32; off >= 1; off >>= 1)
            m = fmaxf(m, __shfl_xor(m, off, 64));

        const float sub = m * bi;
#pragma unroll
        for (int k = 0; k < 4; ++k) {
            float xv[4] = {xa[k].x, xa[k].y, xa[k].z, xa[k].w};
            float ov[4];
#pragma unroll
            for (int j = 0; j < 4; ++j) {
                const int idx = 4 * k + j;
                float vn = v[idx] + (xv[j] - sub);        // v = v + xt
                const bool spike = (vn >= th);            // fire check
                v[idx] = spike ? (vn - th) : vn;          // soft reset (even if blocked)
                const bool blocked = (blockmask >> idx) & 1u;
                ov[j] = (spike && !blocked) ? 1.0f : 0.0f;
                if (spike) blockmask |= (1u << idx);
            }
            float* ot = out + ((size_t)t * NPAIR) * NN + pair_off;
            *(float4*)(ot + 4 * lane + 256 * k) = make_float4(ov[0], ov[1], ov[2], ov[3]);
        }
        if (m > 0.0f) bi = 0.0f;
        th *= 0.5f;                                       // th /= tau (exact)
    }
}

extern "C" void kernel_launch(void* const* d_in, const int* in_sizes, int n_in,
                              void* d_out, int out_size, void* d_ws, size_t ws_size,
                              hipStream_t stream) {
    const float* x = (const float*)d_in[0];
    float* out = (float*)d_out;
    // 2048 waves, 4 waves per 256-thread block -> 512 blocks
    wta_kernel<<<dim3(NPAIR / 4), dim3(256), 0, stream>>>(x, out);
}

// Round 3
// 102.779 us; speedup vs baseline: 1.1025x; 1.1025x over previous
//
#include <hip/hip_runtime.h>

// WTA_layer_Neuron: x [T=36, B=32, H=64, N=1024] f32 -> spikes (same shape).
// One wave (64 lanes) per (b,h) pair: 2048 pairs, 16 neurons/lane.
// R2: software prefetch (distance 1, register double-buffer) + non-temporal
// loads/stores (stream-once data). Uses ext_vector_type since
// __builtin_nontemporal_* rejects HIP_vector_type<float,4>.

constexpr int T_TOTAL = 36;
constexpr int T_FIRE0 = 12;          // START + WAIT
constexpr int NPAIR   = 32 * 64;     // B * H = 2048
constexpr int NN      = 1024;        // neurons per pair

using f32x4 = __attribute__((ext_vector_type(4))) float;

__device__ __forceinline__ void load4(f32x4 (&xa)[4], const float* __restrict__ xt, int lane) {
#pragma unroll
    for (int k = 0; k < 4; ++k)
        xa[k] = __builtin_nontemporal_load((const f32x4*)(xt + 4 * lane + 256 * k));
}

template <bool FIRE>
__device__ __forceinline__ void process_step(const f32x4 (&xa)[4], float (&v)[16],
                                             unsigned& blockmask, float& bi, float& th,
                                             float* __restrict__ ot, int lane) {
    // wave max over this pair's 1024 elements
    float m = xa[0][0];
#pragma unroll
    for (int k = 0; k < 4; ++k)
        m = fmaxf(m, fmaxf(fmaxf(xa[k][0], xa[k][1]), fmaxf(xa[k][2], xa[k][3])));
#pragma unroll
    for (int off = 32; off >= 1; off >>= 1)
        m = fmaxf(m, __shfl_xor(m, off, 64));

    const float sub = m * bi;                 // exact: bi in {0,1}
    if (!FIRE) {
        // charge-only: v += xt - sub, output all zeros
#pragma unroll
        for (int k = 0; k < 4; ++k) {
#pragma unroll
            for (int j = 0; j < 4; ++j)
                v[4 * k + j] += xa[k][j] - sub;
        }
        const f32x4 z = {0.f, 0.f, 0.f, 0.f};
#pragma unroll
        for (int k = 0; k < 4; ++k)
            __builtin_nontemporal_store(z, (f32x4*)(ot + 4 * lane + 256 * k));
    } else {
#pragma unroll
        for (int k = 0; k < 4; ++k) {
            f32x4 ov;
#pragma unroll
            for (int j = 0; j < 4; ++j) {
                const int idx = 4 * k + j;
                float vn = v[idx] + (xa[k][j] - sub);   // v = v + xt
                const bool spike = (vn >= th);          // fire check
                v[idx] = spike ? (vn - th) : vn;        // soft reset (even if blocked)
                const bool blocked = (blockmask >> idx) & 1u;
                ov[j] = (spike && !blocked) ? 1.0f : 0.0f;
                if (spike) blockmask |= (1u << idx);
            }
            __builtin_nontemporal_store(ov, (f32x4*)(ot + 4 * lane + 256 * k));
        }
        th *= 0.5f;                                     // th /= tau (exact)
    }
    if (m > 0.0f) bi = 0.0f;
}

__global__ __launch_bounds__(256) void wta_kernel(const float* __restrict__ x,
                                                  float* __restrict__ out) {
    const int gtid = blockIdx.x * 256 + threadIdx.x;
    const int pair = gtid >> 6;                  // wave id = (b,h) pair
    const int lane = threadIdx.x & 63;
    const size_t pair_off = (size_t)pair * NN;

    float v[16];
#pragma unroll
    for (int i = 0; i < 16; ++i) v[i] = 0.0f;
    unsigned blockmask = 0;
    float bi = 1.0f;                             // block_input (wave-uniform)

    // V_TH0 = 2^23 / (1/ln 2) / 2, f64 exactly as numpy does.
    const double ln2 = 0.6931471805599453;
    float th = (float)(8388608.0 / (1.0 / ln2) / 2.0);

    const float* xb = x + pair_off;
    float* ob = out + pair_off;
    const size_t stride = (size_t)NPAIR * NN;    // per-timestep stride

    f32x4 A[4], B[4];
    load4(A, xb, lane);                          // t = 0

    // ---- Phase 1: t in [0,12), 2-unrolled with prefetch ----
    for (int t = 0; t < T_FIRE0; t += 2) {
        load4(B, xb + (size_t)(t + 1) * stride, lane);
        process_step<false>(A, v, blockmask, bi, th, ob + (size_t)t * stride, lane);
        load4(A, xb + (size_t)(t + 2) * stride, lane);   // t+2 <= 13 < 36, always valid
        process_step<false>(B, v, blockmask, bi, th, ob + (size_t)(t + 1) * stride, lane);
    }

    // ---- Phase 2: t in [12,34), A already holds t=12 ----
    for (int t = T_FIRE0; t < T_TOTAL - 2; t += 2) {
        load4(B, xb + (size_t)(t + 1) * stride, lane);
        process_step<true>(A, v, blockmask, bi, th, ob + (size_t)t * stride, lane);
        load4(A, xb + (size_t)(t + 2) * stride, lane);
        process_step<true>(B, v, blockmask, bi, th, ob + (size_t)(t + 1) * stride, lane);
    }
    // ---- tail: t = 34, 35 ----
    {
        const int t = T_TOTAL - 2;
        load4(B, xb + (size_t)(t + 1) * stride, lane);
        process_step<true>(A, v, blockmask, bi, th, ob + (size_t)t * stride, lane);
        process_step<true>(B, v, blockmask, bi, th, ob + (size_t)(t + 1) * stride, lane);
    }
}

extern "C" void kernel_launch(void* const* d_in, const int* in_sizes, int n_in,
                              void* d_out, int out_size, void* d_ws, size_t ws_size,
                              hipStream_t stream) {
    const float* x = (const float*)d_in[0];
    float* out = (float*)d_out;
    // 2048 waves, 4 waves per 256-thread block -> 512 blocks
    wta_kernel<<<dim3(NPAIR / 4), dim3(256), 0, stream>>>(x, out);
}